// Round 2
// baseline (425.775 us; speedup 1.0000x reference)
//
#include <hip/hip_runtime.h>
#include <hip/hip_fp16.h>
#include <math.h>

#define KK 25
#define H1C 32
#define H2C 64
#define FCC 128
#define NCLS 10
#define NG 64
#define M1 32      // nodes per block, layer-1
#define M2 16      // nodes per block, layer-2
#define SROW 804   // S row stride in floats (800 data + 4 pad; 804%32==4 -> <=2-way banks)

typedef _Float16 v8h __attribute__((ext_vector_type(8)));
typedef float v4f __attribute__((ext_vector_type(4)));

// ---------------- degree via global atomics + weight prep (W2o, r2t) --------
// W2o: [64][800] fp16, o-major, kc=(k*32+c) contiguous  (MFMA B operand)
// r2t: [64][32]  fp16, o-major, c contiguous            (root2 B operand)
__global__ __launch_bounds__(256) void deg_kernel(
    const int* __restrict__ edge_index, int E,
    int* __restrict__ degi,
    const float* __restrict__ W2, __half* __restrict__ W2o,
    const float* __restrict__ root2, __half* __restrict__ r2t) {
    int i = blockIdx.x * 256 + threadIdx.x;
    if (i < KK * H1C * H2C) {           // i = (k*32+c)*64 + o
        int o = i & 63, kc = i >> 6;
        W2o[(size_t)o * (KK * H1C) + kc] = __float2half(W2[i]);
    }
    if (i < H1C * H2C) {                // i = c*64 + o
        int o = i & 63, c = i >> 6;
        r2t[o * H1C + c] = __float2half(root2[i]);
    }
    if (i < E) atomicAdd(&degi[edge_index[E + i]], 1);
}

// ---------------- prefix-sum (3-kernel) over degi -> rowst, cur ----------------
__global__ void scan1_kernel(const int* __restrict__ degi, int N,
                             int* __restrict__ incl, int* __restrict__ bsum) {
    __shared__ int s[256];
    int tid = threadIdx.x;
    int i = blockIdx.x * 256 + tid;
    int v = (i < N) ? degi[i] : 0;
    s[tid] = v;
    __syncthreads();
    for (int off = 1; off < 256; off <<= 1) {
        int t = (tid >= off) ? s[tid - off] : 0;
        __syncthreads();
        s[tid] += t;
        __syncthreads();
    }
    if (i < N) incl[i] = s[tid];
    if (tid == 255) bsum[blockIdx.x] = s[255];
}

__global__ void scan2_kernel(int* __restrict__ bsum, int nb) {
    __shared__ int s[256];
    int tid = threadIdx.x;
    int v = (tid < nb) ? bsum[tid] : 0;
    s[tid] = v;
    __syncthreads();
    for (int off = 1; off < 256; off <<= 1) {
        int t = (tid >= off) ? s[tid - off] : 0;
        __syncthreads();
        s[tid] += t;
        __syncthreads();
    }
    if (tid < nb) bsum[tid] = s[tid] - v;   // exclusive
}

__global__ void scan3_kernel(const int* __restrict__ incl, const int* __restrict__ degi,
                             const int* __restrict__ bsum, int N,
                             int* __restrict__ rowst, int* __restrict__ cur) {
    int i = blockIdx.x * 256 + threadIdx.x;
    if (i >= N) return;
    int r = incl[i] - degi[i] + bsum[blockIdx.x];
    rowst[i] = r;
    cur[i] = r;
}

// ---------------- bucket edges by dst; 16B packed {src, dst<<8|kbase, f0, f1} --
__global__ void bucket_kernel(const float* __restrict__ edge_attr,
                              const int* __restrict__ edge_index, int E,
                              int* __restrict__ cur, int4* __restrict__ es) {
    int e = blockIdx.x * blockDim.x + threadIdx.x;
    if (e >= E) return;
    float v0 = edge_attr[2 * e + 0] * 4.0f;
    float v1 = edge_attr[2 * e + 1] * 4.0f;
    int k0 = (int)floorf(v0); k0 = min(max(k0, 0), 3);
    int k1 = (int)floorf(v1); k1 = min(max(k1, 0), 3);
    float f0 = v0 - (float)k0, f1 = v1 - (float)k1;
    int dst = edge_index[E + e];
    int pos = atomicAdd(&cur[dst], 1);
    es[pos] = make_int4(edge_index[e], (dst << 8) | (k0 + 5 * k1),
                        __float_as_int(f0), __float_as_int(f1));
}

// ---------------- layer 1: CSR gather, register accumulate, boundary flush ----
__global__ __launch_bounds__(256) void l1_kernel(
    const float* __restrict__ x,
    const int* __restrict__ rowst, const int* __restrict__ degi,
    const int4* __restrict__ es,
    const float* __restrict__ W1, const float* __restrict__ root1,
    const float* __restrict__ b1, int N, int E,
    __half* __restrict__ h1f) {
    __shared__ float w1s[KK * H1C];
    __shared__ float agg1[M1 * H1C];
    __shared__ int4 eb[8][32];
    __shared__ float xb[8][32];
    int tid = threadIdx.x;
    for (int i = tid; i < KK * H1C; i += 256) w1s[i] = W1[i];
    for (int i = tid; i < M1 * H1C; i += 256) agg1[i] = 0.0f;
    __syncthreads();
    int g = tid >> 5, o = tid & 31;
    int n0 = blockIdx.x * M1;
    int blkBeg = rowst[n0];
    int blkEnd = (n0 + M1 < N) ? rowst[n0 + M1] : E;
    int total = blkEnd - blkBeg;
    int per = (total + 7) >> 3;
    int wBeg = blkBeg + g * per;
    int wEnd = min(blkEnd, wBeg + per);
    int curDst = -1;
    float acc = 0.0f;
    for (int base = wBeg; base < wEnd; base += 32) {
        int m = min(32, wEnd - base);
        if (o < m) {
            int4 ed = es[base + o];
            eb[g][o] = ed;
            xb[g][o] = x[ed.x];
        }
        for (int j = 0; j < m; j++) {
            int4 ed = eb[g][j];
            float xs = xb[g][j];
            int dst = ed.y >> 8;
            if (dst != curDst) {
                if (curDst >= 0) atomicAdd(&agg1[(curDst - n0) * H1C + o], acc);
                acc = 0.0f;
                curDst = dst;
            }
            float f0 = __int_as_float(ed.z), f1 = __int_as_float(ed.w);
            float g0 = 1.0f - f0, g1 = 1.0f - f1;
            int kb = (ed.y & 0xff) << 5;
            float coef = g0 * g1 * w1s[kb + o] + f0 * g1 * w1s[kb + 32 + o] +
                         g0 * f1 * w1s[kb + 160 + o] + f0 * f1 * w1s[kb + 192 + o];
            acc = fmaf(xs, coef, acc);
        }
    }
    if (curDst >= 0) atomicAdd(&agg1[(curDst - n0) * H1C + o], acc);
    __syncthreads();
#pragma unroll
    for (int i = 0; i < 4; i++) {
        int ln = g + 8 * i;
        int n = n0 + ln;
        if (n < N) {
            float rdeg = 1.0f / fmaxf((float)degi[n], 1.0f);
            float hv = fmaxf(agg1[ln * H1C + o] * rdeg + x[n] * root1[o] + b1[o], 0.0f);
            h1f[n * H1C + o] = __float2half(hv);
        }
    }
}

// ---------------- fused layer 2: basis-space scatter + MFMA contraction ------
// S[dst][k][c] = sum_e b_{e,k} * h1[src_e][c]   (LDS, fp32, ds_add atomics)
// then  h2 = relu( (S @ W2) / deg + h1 @ root2 + b2 )  via MFMA, then pool.
__global__ __launch_bounds__(256) void l2f_kernel(
    const __half* __restrict__ h1f,     // [N][32] fp16
    const int* __restrict__ rowst, const int* __restrict__ degi,
    const int4* __restrict__ es,
    const __half* __restrict__ W2o,     // [64][800] fp16
    const __half* __restrict__ r2t,     // [64][32] fp16
    const float* __restrict__ b2,
    const int* __restrict__ batch,
    int N, int E, float* __restrict__ gsum) {
    __shared__ float S[M2 * SROW];      // 16 x 804 fp32 = 51456 B
    __shared__ int4 eb[4][64];          // 4096 B
    __shared__ float h2s[M2 * H2C];     // 4096 B
    int tid = threadIdx.x;
    for (int i = tid; i < M2 * SROW; i += 256) S[i] = 0.0f;
    __syncthreads();

    int w = tid >> 6, lane = tid & 63;
    int o2 = lane & 31, eh = lane >> 5;
    int n0 = blockIdx.x * M2;
    int blkBeg = rowst[n0];
    int blkEnd = (n0 + M2 < N) ? rowst[n0 + M2] : E;
    int total = blkEnd - blkBeg;
    int per = (total + 3) >> 2;
    int wBeg = blkBeg + w * per;
    int wEnd = min(blkEnd, wBeg + per);

    // Phase A: scatter-accumulate basis-weighted h1 into S
    for (int base = wBeg; base < wEnd; base += 64) {
        int m = min(64, wEnd - base);
        if (lane < m) eb[w][lane] = es[base + lane];
        for (int j = 0; j < m; j += 2) {
            int jj = j + eh;
            if (jj < m) {
                int4 ed = eb[w][jj];
                float xv = __half2float(h1f[(size_t)ed.x * H1C + o2]);
                int dstl = (ed.y >> 8) - n0;
                int kb = ed.y & 0xff;
                float f0 = __int_as_float(ed.z), f1 = __int_as_float(ed.w);
                float g0 = 1.0f - f0, g1 = 1.0f - f1;
                float* row = &S[dstl * SROW + (kb << 5) + o2];
                atomicAdd(row,       g0 * g1 * xv);
                atomicAdd(row + 32,  f0 * g1 * xv);
                atomicAdd(row + 160, g0 * f1 * xv);
                atomicAdd(row + 192, f0 * f1 * xv);
            }
        }
    }
    __syncthreads();

    // Phase B: per-wave MFMA contraction. wave w owns o-tile [16w, 16w+16).
    int r15 = lane & 15, quad = lane >> 4;
    int o0 = w * 16;
    v4f acc = {};
    v4f acc2 = {};
    const float* arow = &S[r15 * SROW + quad * 8];
    const __half* brow = W2o + (size_t)(o0 + r15) * (KK * H1C) + quad * 8;
#pragma unroll
    for (int kk = 0; kk < KK; kk++) {
        v4f lo = *(const v4f*)(arow + (kk << 5));
        v4f hi = *(const v4f*)(arow + (kk << 5) + 4);
        v8h ah;
        ah[0] = (_Float16)lo[0]; ah[1] = (_Float16)lo[1];
        ah[2] = (_Float16)lo[2]; ah[3] = (_Float16)lo[3];
        ah[4] = (_Float16)hi[0]; ah[5] = (_Float16)hi[1];
        ah[6] = (_Float16)hi[2]; ah[7] = (_Float16)hi[3];
        v8h bh = *(const v8h*)(brow + (kk << 5));
        acc = __builtin_amdgcn_mfma_f32_16x16x32_f16(ah, bh, acc, 0, 0, 0);
    }
    {   // root2 term: h1 @ root2
        int an = n0 + r15;
        v8h ah = {};
        if (an < N) ah = *(const v8h*)(h1f + (size_t)an * H1C + quad * 8);
        v8h bh = *(const v8h*)(r2t + (o0 + r15) * H1C + quad * 8);
        acc2 = __builtin_amdgcn_mfma_f32_16x16x32_f16(ah, bh, acc2, 0, 0, 0);
    }
    int oo = o0 + r15;
    float bb = b2[oo];
#pragma unroll
    for (int r = 0; r < 4; r++) {
        int ln = quad * 4 + r;
        int n = n0 + ln;
        float v = 0.0f;
        if (n < N) {
            float rd = 1.0f / fmaxf((float)degi[n], 1.0f);
            v = fmaxf(acc[r] * rd + acc2[r] + bb, 0.0f);
        }
        h2s[ln * H2C + oo] = v;
    }
    __syncthreads();

    // pool: one atomic per (graph,o) per block
    if (tid < H2C) {
        float run = 0.0f;
        int curg = batch[n0];
        for (int ln = 0; ln < M2; ln++) {
            int n = n0 + ln;
            if (n >= N) break;
            int gg = batch[n];
            if (gg != curg) {
                atomicAdd(&gsum[curg * H2C + tid], run);
                run = 0.0f;
                curg = gg;
            }
            run += h2s[ln * H2C + tid];
        }
        atomicAdd(&gsum[curg * H2C + tid], run);
    }
}

// ---------------- head: count via binary search, FC1+relu, FC2, log_softmax --
__global__ void head_kernel(const float* __restrict__ gsum,
                            const int* __restrict__ batch, int N,
                            const float* __restrict__ Wf1, const float* __restrict__ bf1,
                            const float* __restrict__ Wf2, const float* __restrict__ bf2,
                            float* __restrict__ out) {
    __shared__ float gc[H2C];
    __shared__ float t1[FCC];
    __shared__ float lg[NCLS];
    __shared__ float lse;
    __shared__ float scnt;
    int g = blockIdx.x, tid = threadIdx.x;
    if (tid == 0) {
        int lo = 0, hi = N;
        while (lo < hi) { int m = (lo + hi) >> 1; if (batch[m] < g) lo = m + 1; else hi = m; }
        int lb = lo;
        lo = 0; hi = N;
        while (lo < hi) { int m = (lo + hi) >> 1; if (batch[m] <= g) lo = m + 1; else hi = m; }
        scnt = (float)(lo - lb);
    }
    __syncthreads();
    if (tid < H2C) gc[tid] = gsum[g * H2C + tid] / fmaxf(scnt, 1.0f);
    __syncthreads();
    {
        float acc = bf1[tid];
        for (int c = 0; c < H2C; c++) acc += gc[c] * Wf1[c * FCC + tid];
        t1[tid] = fmaxf(acc, 0.0f);
    }
    __syncthreads();
    if (tid < NCLS) {
        float acc = bf2[tid];
        for (int j = 0; j < FCC; j++) acc += t1[j] * Wf2[j * NCLS + tid];
        lg[tid] = acc;
    }
    __syncthreads();
    if (tid == 0) {
        float m = lg[0];
        for (int c = 1; c < NCLS; c++) m = fmaxf(m, lg[c]);
        float s = 0.0f;
        for (int c = 0; c < NCLS; c++) s += expf(lg[c] - m);
        lse = m + logf(s);
    }
    __syncthreads();
    if (tid < NCLS) out[g * NCLS + tid] = lg[tid] - lse;
}

extern "C" void kernel_launch(void* const* d_in, const int* in_sizes, int n_in,
                              void* d_out, int out_size, void* d_ws, size_t ws_size,
                              hipStream_t stream) {
    const float* x          = (const float*)d_in[0];
    const float* edge_attr  = (const float*)d_in[1];
    const float* W1         = (const float*)d_in[2];
    const float* root1      = (const float*)d_in[3];
    const float* b1         = (const float*)d_in[4];
    const float* W2         = (const float*)d_in[5];
    const float* root2      = (const float*)d_in[6];
    const float* b2         = (const float*)d_in[7];
    const float* Wf1        = (const float*)d_in[8];
    const float* bf1        = (const float*)d_in[9];
    const float* Wf2        = (const float*)d_in[10];
    const float* bf2        = (const float*)d_in[11];
    const int*   edge_index = (const int*)d_in[12];
    const int*   batch      = (const int*)d_in[13];
    float* out = (float*)d_out;

    const int N = in_sizes[13];       // 20000
    const int E = in_sizes[12] / 2;   // 320000
    const int NB = (N + 255) / 256;   // scan blocks

    // -------- workspace layout --------
    int4*   es  = (int4*)d_ws;                            // E packed sorted edges
    __half* W2o = (__half*)(es + E);                      // 64*800 fp16
    __half* r2t = W2o + (size_t)H2C * KK * H1C;           // 64*32 fp16
    __half* h1f = r2t + H2C * H1C;                        // N*32 fp16
    float* gsum = (float*)(h1f + (size_t)N * H1C);        // NG*H2C  -- zeroed
    int*   degi = (int*)(gsum + NG * H2C);                // N       -- zeroed (same memset)
    int*   rowst = degi + N;                              // N
    int*   cur   = rowst + N;                             // N
    int*   incl  = cur + N;                               // N
    int*   bsum  = incl + N;                              // 256

    // single memset covers gsum (NG*H2C floats) + degi (N ints), adjacent
    hipMemsetAsync(gsum, 0, (size_t)NG * H2C * sizeof(float) + (size_t)N * sizeof(int),
                   stream);

    int degBlocks = (E + 255) / 256;   // E > all prep ranges
    deg_kernel<<<degBlocks, 256, 0, stream>>>(edge_index, E, degi, W2, W2o, root2, r2t);

    scan1_kernel<<<NB, 256, 0, stream>>>(degi, N, incl, bsum);
    scan2_kernel<<<1, 256, 0, stream>>>(bsum, NB);
    scan3_kernel<<<NB, 256, 0, stream>>>(incl, degi, bsum, N, rowst, cur);

    bucket_kernel<<<(E + 255) / 256, 256, 0, stream>>>(edge_attr, edge_index, E, cur, es);

    l1_kernel<<<(N + M1 - 1) / M1, 256, 0, stream>>>(
        x, rowst, degi, es, W1, root1, b1, N, E, h1f);

    l2f_kernel<<<(N + M2 - 1) / M2, 256, 0, stream>>>(
        h1f, rowst, degi, es, W2o, r2t, b2, batch, N, E, gsum);

    head_kernel<<<NG, FCC, 0, stream>>>(gsum, batch, N, Wf1, bf1, Wf2, bf2, out);
}

// Round 3
// 213.383 us; speedup vs baseline: 1.9954x; 1.9954x over previous
//
#include <hip/hip_runtime.h>
#include <hip/hip_fp16.h>
#include <math.h>

#define KK 25
#define H1C 32
#define H2C 64
#define FCC 128
#define NCLS 10
#define NG 64
#define M1 32      // nodes per block, layer-1
#define M2 16      // nodes per block, layer-2

typedef _Float16 v8h __attribute__((ext_vector_type(8)));
typedef _Float16 v4h __attribute__((ext_vector_type(4)));
typedef float v4f __attribute__((ext_vector_type(4)));

// ---------------- degree via global atomics (L2-resident counters) ----------
// Also folds in the tiny W2 -> fp16 transposed [25][64][32] conversion.
__global__ __launch_bounds__(256) void deg_kernel(
    const int* __restrict__ edge_index, int E,
    int* __restrict__ degi,
    const float* __restrict__ W2, __half* __restrict__ W2t) {
    int i = blockIdx.x * 256 + threadIdx.x;
    if (i < KK * H2C * H1C) {
        int c = i & 31, o = (i >> 5) & 63, k = i >> 11;
        W2t[i] = __float2half(W2[(k * H1C + c) * H2C + o]);
    }
    if (i < E) atomicAdd(&degi[edge_index[E + i]], 1);
}

// ---------------- prefix-sum (3-kernel) over degi -> rowst, cur ----------------
__global__ void scan1_kernel(const int* __restrict__ degi, int N,
                             int* __restrict__ incl, int* __restrict__ bsum) {
    __shared__ int s[256];
    int tid = threadIdx.x;
    int i = blockIdx.x * 256 + tid;
    int v = (i < N) ? degi[i] : 0;
    s[tid] = v;
    __syncthreads();
    for (int off = 1; off < 256; off <<= 1) {
        int t = (tid >= off) ? s[tid - off] : 0;
        __syncthreads();
        s[tid] += t;
        __syncthreads();
    }
    if (i < N) incl[i] = s[tid];
    if (tid == 255) bsum[blockIdx.x] = s[255];
}

__global__ void scan2_kernel(int* __restrict__ bsum, int nb) {
    __shared__ int s[256];
    int tid = threadIdx.x;
    int v = (tid < nb) ? bsum[tid] : 0;
    s[tid] = v;
    __syncthreads();
    for (int off = 1; off < 256; off <<= 1) {
        int t = (tid >= off) ? s[tid - off] : 0;
        __syncthreads();
        s[tid] += t;
        __syncthreads();
    }
    if (tid < nb) bsum[tid] = s[tid] - v;   // exclusive
}

__global__ void scan3_kernel(const int* __restrict__ incl, const int* __restrict__ degi,
                             const int* __restrict__ bsum, int N,
                             int* __restrict__ rowst, int* __restrict__ cur) {
    int i = blockIdx.x * 256 + threadIdx.x;
    if (i >= N) return;
    int r = incl[i] - degi[i] + bsum[blockIdx.x];
    rowst[i] = r;
    cur[i] = r;
}

// ---------------- bucket edges by dst; 16B packed {src, dst<<8|kbase, f0, f1} --
__global__ void bucket_kernel(const float* __restrict__ edge_attr,
                              const int* __restrict__ edge_index, int E,
                              int* __restrict__ cur, int4* __restrict__ es) {
    int e = blockIdx.x * blockDim.x + threadIdx.x;
    if (e >= E) return;
    float v0 = edge_attr[2 * e + 0] * 4.0f;
    float v1 = edge_attr[2 * e + 1] * 4.0f;
    int k0 = (int)floorf(v0); k0 = min(max(k0, 0), 3);
    int k1 = (int)floorf(v1); k1 = min(max(k1, 0), 3);
    float f0 = v0 - (float)k0, f1 = v1 - (float)k1;
    int dst = edge_index[E + e];
    int pos = atomicAdd(&cur[dst], 1);
    es[pos] = make_int4(edge_index[e], (dst << 8) | (k0 + 5 * k1),
                        __float_as_int(f0), __float_as_int(f1));
}

// ---------------- layer 1 + fused xW2 MFMA -----------------------------------
// Phase A (proven round-1 path): CSR gather, register accumulate, boundary
// flush into LDS agg1; epilogue computes h1 (fp32 global for l2 epilogue) and
// stores fp16 copy into LDS h1s.
// Phase B (fused former xw2m): 4 waves x 2 node-tiles, operand-swapped
// mfma_f32_16x16x32_f16: A=W2t slice (o-major), B=h1s tile. Each lane packs 4
// consecutive o-channels of one node into a single 8B store to xph.
__global__ __launch_bounds__(256) void l1_kernel(
    const float* __restrict__ x,
    const int* __restrict__ rowst, const int* __restrict__ degi,
    const int4* __restrict__ es,
    const float* __restrict__ W1, const float* __restrict__ root1,
    const float* __restrict__ b1,
    const __half* __restrict__ W2t,   // [25][64][32] (c innermost)
    int N, int E,
    float* __restrict__ h1, __half* __restrict__ xph) {
    __shared__ float w1s[KK * H1C];
    __shared__ float agg1[M1 * H1C];
    __shared__ int4 eb[8][32];
    __shared__ float xb[8][32];
    __shared__ __half h1s[M1][H1C];   // fp16 h1 tile for MFMA B operand
    int tid = threadIdx.x;
    for (int i = tid; i < KK * H1C; i += 256) w1s[i] = W1[i];
    for (int i = tid; i < M1 * H1C; i += 256) agg1[i] = 0.0f;
    __syncthreads();
    int g = tid >> 5, o = tid & 31;
    int n0 = blockIdx.x * M1;
    int blkBeg = rowst[n0];
    int blkEnd = (n0 + M1 < N) ? rowst[n0 + M1] : E;
    int total = blkEnd - blkBeg;
    int per = (total + 7) >> 3;
    int wBeg = blkBeg + g * per;
    int wEnd = min(blkEnd, wBeg + per);
    int curDst = -1;
    float acc = 0.0f;
    for (int base = wBeg; base < wEnd; base += 32) {
        int m = min(32, wEnd - base);
        if (o < m) {
            int4 ed = es[base + o];
            eb[g][o] = ed;
            xb[g][o] = x[ed.x];
        }
        for (int j = 0; j < m; j++) {
            int4 ed = eb[g][j];
            float xs = xb[g][j];
            int dst = ed.y >> 8;
            if (dst != curDst) {
                if (curDst >= 0) atomicAdd(&agg1[(curDst - n0) * H1C + o], acc);
                acc = 0.0f;
                curDst = dst;
            }
            float f0 = __int_as_float(ed.z), f1 = __int_as_float(ed.w);
            float g0 = 1.0f - f0, g1 = 1.0f - f1;
            int kb = (ed.y & 0xff) << 5;
            float coef = g0 * g1 * w1s[kb + o] + f0 * g1 * w1s[kb + 32 + o] +
                         g0 * f1 * w1s[kb + 160 + o] + f0 * f1 * w1s[kb + 192 + o];
            acc = fmaf(xs, coef, acc);
        }
    }
    if (curDst >= 0) atomicAdd(&agg1[(curDst - n0) * H1C + o], acc);
    __syncthreads();
#pragma unroll
    for (int i = 0; i < 4; i++) {
        int ln = g + 8 * i;
        int n = n0 + ln;
        if (n < N) {
            float rdeg = 1.0f / fmaxf((float)degi[n], 1.0f);
            float hv = fmaxf(agg1[ln * H1C + o] * rdeg + x[n] * root1[o] + b1[o], 0.0f);
            h1[n * H1C + o] = hv;
            h1s[ln][o] = __float2half(hv);
        } else {
            h1s[ln][o] = __float2half(0.0f);
        }
    }
    __syncthreads();

    // ---- Phase B: xph[n][k][o] for the block's 32 nodes ----
    int w = tid >> 6, lane = tid & 63;
    int r15 = lane & 15, quad = lane >> 4;
    int o0 = w * 16;
#pragma unroll
    for (int nt = 0; nt < 2; nt++) {
        int bn = n0 + nt * 16 + r15;
        bool wr = bn < N;
        v8h bfrag = *(const v8h*)(&h1s[nt * 16 + r15][quad * 8]);
        size_t baseoff = (size_t)bn * (KK * H2C) + o0 + (quad << 2);
        for (int k = 0; k < KK; k++) {
            v8h afrag = *(const v8h*)(W2t + ((k << 6) + o0 + r15) * H1C + quad * 8);
            v4f acc2 = {};
            acc2 = __builtin_amdgcn_mfma_f32_16x16x32_f16(afrag, bfrag, acc2, 0, 0, 0);
            if (wr) {
                v4h hv;
                hv[0] = (_Float16)acc2[0];
                hv[1] = (_Float16)acc2[1];
                hv[2] = (_Float16)acc2[2];
                hv[3] = (_Float16)acc2[3];
                *(v4h*)(xph + baseoff + (k << 6)) = hv;   // 8B aligned packed store
            }
        }
    }
}

// ---------------- layer 2: half2-packed gather + segment accumulate ----------
__global__ __launch_bounds__(256) void l2_kernel(
    const float* __restrict__ h1,
    const int* __restrict__ rowst, const int* __restrict__ degi,
    const int4* __restrict__ es,
    const unsigned* __restrict__ xphu,  // [N][25][32] uints (=2 halves)
    const float* __restrict__ root2, const float* __restrict__ b2,
    const int* __restrict__ batch,
    int N, int E, float* __restrict__ gsum) {
    __shared__ float agg[M2 * H2C];
    __shared__ int4 eb[4][64];
    int tid = threadIdx.x;
    for (int i = tid; i < M2 * H2C; i += 256) agg[i] = 0.0f;
    __syncthreads();
    int w = tid >> 6, lane = tid & 63;
    int o2 = lane & 31, eh = lane >> 5;
    int n0 = blockIdx.x * M2;
    int blkBeg = rowst[n0];
    int blkEnd = (n0 + M2 < N) ? rowst[n0 + M2] : E;
    int total = blkEnd - blkBeg;
    int per = (total + 3) >> 2;
    int wBeg = blkBeg + w * per;
    int wEnd = min(blkEnd, wBeg + per);
    int curDst = -1;
    float ax = 0.0f, ay = 0.0f;
    for (int base = wBeg; base < wEnd; base += 64) {
        int m = min(64, wEnd - base);
        if (lane < m) eb[w][lane] = es[base + lane];
        for (int j = 0; j < m; j += 2) {
            int jj = j + eh;
            bool act = jj < m;
            int4 ed = eb[w][act ? jj : j];
            const unsigned* p = xphu + (size_t)ed.x * (KK * H2C / 2) +
                                ((ed.y & 0xff) << 5) + o2;
            unsigned t0 = p[0], t1 = p[32], t2 = p[160], t3 = p[192];
            if (act) {
                int dst = ed.y >> 8;
                if (dst != curDst) {
                    if (curDst >= 0) {
                        atomicAdd(&agg[(curDst - n0) * H2C + 2 * o2], ax);
                        atomicAdd(&agg[(curDst - n0) * H2C + 2 * o2 + 1], ay);
                    }
                    ax = ay = 0.0f;
                    curDst = dst;
                }
                float f0 = __int_as_float(ed.z), f1 = __int_as_float(ed.w);
                float g0 = 1.0f - f0, g1 = 1.0f - f1;
                float b0 = g0 * g1, b1 = f0 * g1, bb2 = g0 * f1, b3 = f0 * f1;
                __half2 h0 = *(__half2*)&t0, h1v = *(__half2*)&t1;
                __half2 h2 = *(__half2*)&t2, h3 = *(__half2*)&t3;
                ax = fmaf(b0, __low2float(h0), ax);  ay = fmaf(b0, __high2float(h0), ay);
                ax = fmaf(b1, __low2float(h1v), ax); ay = fmaf(b1, __high2float(h1v), ay);
                ax = fmaf(bb2, __low2float(h2), ax); ay = fmaf(bb2, __high2float(h2), ay);
                ax = fmaf(b3, __low2float(h3), ax);  ay = fmaf(b3, __high2float(h3), ay);
            }
        }
    }
    if (curDst >= 0) {
        atomicAdd(&agg[(curDst - n0) * H2C + 2 * o2], ax);
        atomicAdd(&agg[(curDst - n0) * H2C + 2 * o2 + 1], ay);
    }
    __syncthreads();

    // epilogue: h2 = relu(agg/deg + h1@root2 + b2), in place in agg
#pragma unroll
    for (int i = 0; i < 4; i++) {
        int ln = w + 4 * i;
        int n = n0 + ln;
        if (n < N) {
            float rd = 1.0f / fmaxf((float)degi[n], 1.0f);
            float v = agg[ln * H2C + lane] * rd + b2[lane];
            const float* hr = h1 + n * H1C;
#pragma unroll 8
            for (int c = 0; c < H1C; c++) v = fmaf(hr[c], root2[c * H2C + lane], v);
            agg[ln * H2C + lane] = fmaxf(v, 0.0f);
        } else {
            agg[ln * H2C + lane] = 0.0f;
        }
    }
    __syncthreads();

    // pool: one atomic per (graph,o) per block
    if (tid < H2C) {
        float run = 0.0f;
        int curg = batch[n0];
        for (int ln = 0; ln < M2; ln++) {
            int n = n0 + ln;
            if (n >= N) break;
            int gg = batch[n];
            if (gg != curg) {
                atomicAdd(&gsum[curg * H2C + tid], run);
                run = 0.0f;
                curg = gg;
            }
            run += agg[ln * H2C + tid];
        }
        atomicAdd(&gsum[curg * H2C + tid], run);
    }
}

// ---------------- head: count via binary search, FC1+relu, FC2, log_softmax --
__global__ void head_kernel(const float* __restrict__ gsum,
                            const int* __restrict__ batch, int N,
                            const float* __restrict__ Wf1, const float* __restrict__ bf1,
                            const float* __restrict__ Wf2, const float* __restrict__ bf2,
                            float* __restrict__ out) {
    __shared__ float gc[H2C];
    __shared__ float t1[FCC];
    __shared__ float lg[NCLS];
    __shared__ float lse;
    __shared__ float scnt;
    int g = blockIdx.x, tid = threadIdx.x;
    if (tid == 0) {
        int lo = 0, hi = N;
        while (lo < hi) { int m = (lo + hi) >> 1; if (batch[m] < g) lo = m + 1; else hi = m; }
        int lb = lo;
        lo = 0; hi = N;
        while (lo < hi) { int m = (lo + hi) >> 1; if (batch[m] <= g) lo = m + 1; else hi = m; }
        scnt = (float)(lo - lb);
    }
    __syncthreads();
    if (tid < H2C) gc[tid] = gsum[g * H2C + tid] / fmaxf(scnt, 1.0f);
    __syncthreads();
    {
        float acc = bf1[tid];
        for (int c = 0; c < H2C; c++) acc += gc[c] * Wf1[c * FCC + tid];
        t1[tid] = fmaxf(acc, 0.0f);
    }
    __syncthreads();
    if (tid < NCLS) {
        float acc = bf2[tid];
        for (int j = 0; j < FCC; j++) acc += t1[j] * Wf2[j * NCLS + tid];
        lg[tid] = acc;
    }
    __syncthreads();
    if (tid == 0) {
        float m = lg[0];
        for (int c = 1; c < NCLS; c++) m = fmaxf(m, lg[c]);
        float s = 0.0f;
        for (int c = 0; c < NCLS; c++) s += expf(lg[c] - m);
        lse = m + logf(s);
    }
    __syncthreads();
    if (tid < NCLS) out[g * NCLS + tid] = lg[tid] - lse;
}

extern "C" void kernel_launch(void* const* d_in, const int* in_sizes, int n_in,
                              void* d_out, int out_size, void* d_ws, size_t ws_size,
                              hipStream_t stream) {
    const float* x          = (const float*)d_in[0];
    const float* edge_attr  = (const float*)d_in[1];
    const float* W1         = (const float*)d_in[2];
    const float* root1      = (const float*)d_in[3];
    const float* b1         = (const float*)d_in[4];
    const float* W2         = (const float*)d_in[5];
    const float* root2      = (const float*)d_in[6];
    const float* b2         = (const float*)d_in[7];
    const float* Wf1        = (const float*)d_in[8];
    const float* bf1        = (const float*)d_in[9];
    const float* Wf2        = (const float*)d_in[10];
    const float* bf2        = (const float*)d_in[11];
    const int*   edge_index = (const int*)d_in[12];
    const int*   batch      = (const int*)d_in[13];
    float* out = (float*)d_out;

    const int N = in_sizes[13];       // 20000
    const int E = in_sizes[12] / 2;   // 320000
    const int NB = (N + 255) / 256;   // scan blocks

    // -------- workspace layout --------
    int4*     es   = (int4*)d_ws;                        // E packed sorted edges
    unsigned* xphu = (unsigned*)(es + E);                // N*800 uints = fp16 [N][25][64]
    __half*   w2t  = (__half*)(xphu + (size_t)N * 800);  // 25*64*32 halves
    float* gsum  = (float*)(w2t + KK * H2C * H1C);       // NG*H2C  -- zeroed
    int*   degi  = (int*)(gsum + NG * H2C);              // N       -- zeroed (same memset)
    int*   rowst = degi + N;                             // N
    int*   cur   = rowst + N;                            // N
    int*   incl  = cur + N;                              // N
    int*   bsum  = incl + N;                             // 256
    float* h1    = (float*)(bsum + 256);                 // N*H1C

    // single memset covers gsum (NG*H2C floats) + degi (N ints), adjacent
    hipMemsetAsync(gsum, 0, (size_t)NG * H2C * sizeof(float) + (size_t)N * sizeof(int),
                   stream);

    int degBlocks = (E + 255) / 256;
    deg_kernel<<<degBlocks, 256, 0, stream>>>(edge_index, E, degi, W2, w2t);

    scan1_kernel<<<NB, 256, 0, stream>>>(degi, N, incl, bsum);
    scan2_kernel<<<1, 256, 0, stream>>>(bsum, NB);
    scan3_kernel<<<NB, 256, 0, stream>>>(incl, degi, bsum, N, rowst, cur);

    bucket_kernel<<<(E + 255) / 256, 256, 0, stream>>>(edge_attr, edge_index, E, cur, es);

    l1_kernel<<<(N + M1 - 1) / M1, 256, 0, stream>>>(
        x, rowst, degi, es, W1, root1, b1, w2t, N, E, h1, (__half*)xphu);

    l2_kernel<<<(N + M2 - 1) / M2, 256, 0, stream>>>(
        h1, rowst, degi, es, xphu, root2, b2, batch, N, E, gsum);

    head_kernel<<<NG, FCC, 0, stream>>>(gsum, batch, N, Wf1, bf1, Wf2, bf2, out);
}